// Round 6
// baseline (506.428 us; speedup 1.0000x reference)
//
#include <hip/hip_runtime.h>
#include <math.h>

// EncoderBlock: pre-LN attention + FFN, bf16 MFMA compute, fp32 residual spine.
// B=4 T=2048 D=1024 H=16 dk=64 DFF=4096
// R1: XOR-swizzle attn LDS tiles; q pre-scaled.
// R2: V^T staged via global_load_lds; KVBLK=128; exp2 softmax; defer-max.
// R3: swapped QK^T -> lane-local P; PV via 16x16x16f16 from P registers.
// R4: 256x128-tile 8-wave GEMM (T1/T2/T5).
// R5: GEMM -> 3-buffer rotation, full-K-tile prefetch depth, vmcnt(6) once
//     per K-tile (m201-style counted waits). Attn: setprio + l-sum via
//     ones-fragment MFMA (kills sum-reduce VALU + epilogue shuffles).

#define D_MODEL 1024
#define D_FF    4096
#define NH      16
#define BATCH   4
#define SEQ     2048
#define DK      64
#define MTOK    (BATCH*SEQ)   // 8192
#define NBH     (BATCH*NH)    // 64

typedef __bf16 bf16;
typedef _Float16 f16;
typedef bf16  bf16x4 __attribute__((ext_vector_type(4)));
typedef bf16  bf16x8 __attribute__((ext_vector_type(8)));
typedef f16   f16x4  __attribute__((ext_vector_type(4)));
typedef float f32x4  __attribute__((ext_vector_type(4)));

__device__ __forceinline__ void gload_lds16(const void* g, void* l) {
  __builtin_amdgcn_global_load_lds(
      (__attribute__((address_space(1))) void*)g,
      (__attribute__((address_space(3))) void*)l, 16, 0, 0);
}

#define BAR() __builtin_amdgcn_s_barrier()
#define WAIT_VM6() do { asm volatile("s_waitcnt vmcnt(6)" ::: "memory"); \
  __builtin_amdgcn_sched_barrier(0); } while (0)
#define WAIT_VM0() do { asm volatile("s_waitcnt vmcnt(0)" ::: "memory"); \
  __builtin_amdgcn_sched_barrier(0); } while (0)
#define WAIT_LGKM0() do { asm volatile("s_waitcnt lgkmcnt(0)" ::: "memory"); } while (0)

// ---------------- fp32 -> bf16 cast (weights) ----------------
__global__ __launch_bounds__(256) void cast_w(const float* __restrict__ s,
                                              bf16* __restrict__ d, int n) {
  int i = (blockIdx.x * 256 + threadIdx.x) * 4;
  if (i >= n) return;
  float4 v = *(const float4*)(s + i);
  bf16x4 o;
  o[0] = (bf16)v.x; o[1] = (bf16)v.y; o[2] = (bf16)v.z; o[3] = (bf16)v.w;
  *(bf16x4*)(d + i) = o;
}

// ---------------- LayerNorm (fp32 in, bf16 out) ----------------
__global__ __launch_bounds__(256) void ln_kernel(const float* __restrict__ x,
                                                 const float* __restrict__ g,
                                                 const float* __restrict__ b,
                                                 bf16* __restrict__ out) {
  int row = blockIdx.x;
  int tid = threadIdx.x;
  const float* xr = x + (size_t)row * D_MODEL;
  float4 v = *(const float4*)(xr + tid * 4);
  float s  = v.x + v.y + v.z + v.w;
  float sq = v.x*v.x + v.y*v.y + v.z*v.z + v.w*v.w;
  #pragma unroll
  for (int off = 1; off < 64; off <<= 1) {
    s  += __shfl_xor(s,  off, 64);
    sq += __shfl_xor(sq, off, 64);
  }
  __shared__ float ls[4], lq[4];
  int wid = tid >> 6, lane = tid & 63;
  if (lane == 0) { ls[wid] = s; lq[wid] = sq; }
  __syncthreads();
  s  = ls[0] + ls[1] + ls[2] + ls[3];
  sq = lq[0] + lq[1] + lq[2] + lq[3];
  float mu   = s * (1.0f / D_MODEL);
  float var  = sq * (1.0f / D_MODEL) - mu * mu;
  float rstd = rsqrtf(var + 1e-5f);
  float4 gv = *(const float4*)(g + tid * 4);
  float4 bv = *(const float4*)(b + tid * 4);
  bf16x4 o;
  o[0] = (bf16)((v.x - mu) * rstd * gv.x + bv.x);
  o[1] = (bf16)((v.y - mu) * rstd * gv.y + bv.y);
  o[2] = (bf16)((v.z - mu) * rstd * gv.z + bv.z);
  o[3] = (bf16)((v.w - mu) * rstd * gv.w + bv.w);
  *(bf16x4*)(out + (size_t)row * D_MODEL + tid * 4) = o;
}

// ---------------- GEMM: C[M,N] = A[M,K] @ W[N,K]^T (+bias, epilogue) --------
// 256x128 tile, BK=64, 8 waves (4m x 2n, wave-tile 64x64).
// 3 LDS buffers (48KB each, 144KB total, 1 block/CU), rotation bc/bn1/bn2:
// iter t reads bc (tile t), stages tile t+2 into bn2 (3 loads/phase, 6/iter),
// waits vmcnt(6) ONCE at iter end (ensures tile t+1 resident, leaves t+2's 6
// in flight) -> ~2.5 phases of latency cover. Tail: vmcnt(0) at t==nt-2.
enum { EP_QKV = 0, EP_RESID = 1, EP_GELU = 2 };

#define QSCALE 0.18033688011112042f  // (1/8) * log2(e)

template <int EP>
__global__ __launch_bounds__(512) void gemm256(
    const bf16* __restrict__ A, const bf16* __restrict__ W,
    const float* __restrict__ bias,
    const float* __restrict__ resid,
    float* __restrict__ out_f32,
    bf16* __restrict__ out_bf,
    int M, int N, int K) {
  __shared__ char lds[3 * 49152];  // per buf: A 2kh x 256 x 32 (32K) + B 2kh x 128 x 32 (16K)
  int tiles_n = N >> 7;
  int nwg = (M >> 8) * tiles_n;
  int bid = blockIdx.x;
  int swz = (bid & 7) * (nwg >> 3) + (bid >> 3);   // XCD-contiguous chunks
  int bm = swz / tiles_n, bn = swz % tiles_n;
  int m0 = bm << 8, n0 = bn << 7;
  int tid = threadIdx.x, wid = tid >> 6, lane = tid & 63;
  int wm = wid >> 1, wn = wid & 1;
  int l15 = lane & 15, l4 = lane >> 4;
  int gsw = (l4 ^ (l15 & 3)) << 4;                 // read-side granule swizzle (bytes)
  int csw = ((tid & 3) ^ ((tid >> 2) & 3)) << 3;   // stage-side source col swizzle (elems)
  int rT  = tid >> 2;                              // staging row within half

  f32x4 acc[4][4];
  #pragma unroll
  for (int i = 0; i < 4; i++)
    #pragma unroll
    for (int j = 0; j < 4; j++)
      #pragma unroll
      for (int e = 0; e < 4; e++) acc[i][j][e] = 0.f;

  const size_t rowAa = (size_t)(m0 + rT) * K;
  const size_t rowAb = (size_t)(m0 + 128 + rT) * K;
  const size_t rowB  = (size_t)(n0 + rT) * K;

  // STAGE one k-half (kh) of K-tile kt into buffer dst: 3 gload_lds/thread.
  auto STAGE = [&](int kh, int kt, char* dst) {
    size_t koff = (size_t)kt * 64 + kh * 32 + csw;
    char* dA = dst + kh * 16384 + (wid << 10);
    char* dB = dst + 32768 + kh * 8192 + (wid << 10);
    gload_lds16(A + rowAa + koff, dA);
    gload_lds16(A + rowAb + koff, dA + 8192);
    gload_lds16(W + rowB + koff, dB);
  };

  int nt = K >> 6;
  char* bc  = lds;
  char* bn1 = lds + 49152;
  char* bn2 = lds + 2 * 49152;

  STAGE(0, 0, bc);  STAGE(1, 0, bc);
  STAGE(0, 1, bn1); STAGE(1, 1, bn1);
  WAIT_VM6();  // tile 0 resident, tile 1's 6 in flight
  BAR();

  for (int t = 0; t < nt; ++t) {
    bool ds_ = (t + 2) < nt;
    #pragma unroll
    for (int kh = 0; kh < 2; ++kh) {
      bf16x8 af[4], bq[4];
      const char* pa_ = bc + kh * 16384 + gsw;
      const char* pb_ = bc + 32768 + kh * 8192 + gsw;
      #pragma unroll
      for (int i = 0; i < 4; i++)
        af[i] = *(const bf16x8*)(pa_ + (wm * 64 + i * 16 + l15) * 64);
      #pragma unroll
      for (int j = 0; j < 4; j++)
        bq[j] = *(const bf16x8*)(pb_ + (wn * 64 + j * 16 + l15) * 64);
      if (ds_) STAGE(kh, t + 2, bn2);
      BAR();
      WAIT_LGKM0();
      __builtin_amdgcn_s_setprio(1);
      #pragma unroll
      for (int i = 0; i < 4; i++)
        #pragma unroll
        for (int j = 0; j < 4; j++)
          acc[i][j] = __builtin_amdgcn_mfma_f32_16x16x32_bf16(af[i], bq[j], acc[i][j], 0, 0, 0);
      __builtin_amdgcn_s_setprio(0);
      if (kh == 1) {
        if (t < nt - 2) { WAIT_VM6(); }
        else            { WAIT_VM0(); }
      }
      BAR();
    }
    char* tmp = bc; bc = bn1; bn1 = bn2; bn2 = tmp;
  }

  // ----- epilogue -----
  if (EP == EP_QKV) {
    #pragma unroll
    for (int i = 0; i < 4; i++)
      #pragma unroll
      for (int j = 0; j < 4; j++) {
        int gm0 = m0 + wm * 64 + i * 16 + (l4 << 2);
        int gn  = n0 + wn * 64 + j * 16 + l15;
        int which = gn >> 10;
        int nn = gn & 1023, head = nn >> 6, d = nn & 63;
        int bb = gm0 >> 11, t = gm0 & 2047;
        float bv = bias[gn];
        if (which == 2) {
          f16x4 pk;
          #pragma unroll
          for (int jj = 0; jj < 4; jj++) pk[jj] = (f16)(acc[i][j][jj] + bv);
          *(f16x4*)((f16*)out_bf + (size_t)2 * NBH * SEQ * DK +
                    ((size_t)(bb * NH + head) * DK + d) * SEQ + t) = pk;
        } else {
          float scale = (which == 0) ? QSCALE : 1.0f;
          #pragma unroll
          for (int jj = 0; jj < 4; jj++) {
            float cv = (acc[i][j][jj] + bv) * scale;
            size_t idx = (size_t)which * (NBH * SEQ * DK) +
                         ((size_t)(bb * NH + head) * SEQ + (t + jj)) * DK + d;
            out_bf[idx] = (bf16)cv;
          }
        }
      }
  } else {
    #pragma unroll
    for (int i = 0; i < 4; i++)
      #pragma unroll
      for (int j = 0; j < 4; j++)
        #pragma unroll
        for (int jj = 0; jj < 4; jj++) {
          int gm = m0 + wm * 64 + i * 16 + (l4 << 2) + jj;
          int gn = n0 + wn * 64 + j * 16 + l15;
          float cv = acc[i][j][jj] + bias[gn];
          if (EP == EP_RESID) {
            size_t idx = (size_t)gm * N + gn;
            out_f32[idx] = resid[idx] + cv;
          } else {
            float ge = 0.5f * cv * (1.0f + erff(cv * 0.70710678118654752f));
            out_bf[(size_t)gm * N + gn] = (bf16)ge;
          }
        }
  }
}

// ---------------- Flash attention (register-resident P) ----------------
// l-sum computed via MFMA with all-ones B-fragment: acc_l[j] = l[q=l4*4+j],
// same D-layout as acc_o -> no shuffles for sum-reduce or epilogue.
__global__ __launch_bounds__(256) void attn_kernel(
    const bf16* __restrict__ q, const bf16* __restrict__ k,
    const f16* __restrict__ vt, bf16* __restrict__ o) {
  __shared__ bf16 kt_lds[128 * 64];     // [kv][dk], granule16 ^= row&7
  __shared__ f16  vt_lds[64 * 128];     // [d][kv],  granule16 ^= row&15
  int bid = blockIdx.x;
  int bh = bid >> 5;
  int qt = bid & 31;
  int t0 = qt << 6;
  int tid = threadIdx.x, wid = tid >> 6, lane = tid & 63;
  int l15 = lane & 15, l4 = lane >> 4;

  const bf16* qbase = q + ((size_t)bh * SEQ + t0 + wid * 16 + l15) * DK;
  bf16x8 qf[2];
  qf[0] = *(const bf16x8*)(qbase + (l4 << 3));
  qf[1] = *(const bf16x8*)(qbase + 32 + (l4 << 3));

  const f16x4 vones = {(f16)1.f, (f16)1.f, (f16)1.f, (f16)1.f};
  float m_run = -1e30f;
  f32x4 acc_o[4];
  f32x4 acc_l;
  #pragma unroll
  for (int nd = 0; nd < 4; nd++)
    #pragma unroll
    for (int e = 0; e < 4; e++) acc_o[nd][e] = 0.f;
  #pragma unroll
  for (int e = 0; e < 4; e++) acc_l[e] = 0.f;

  int rK = tid >> 3;
  int cK = ((tid & 7) ^ (rK & 7)) << 3;
  const bf16* gK = k + ((size_t)bh * SEQ + rK) * DK + cK;
  bf16* lK = kt_lds + (wid << 9);
  int rV = tid >> 4;
  int cV = ((tid & 15) ^ rV) << 3;
  const f16* gV = vt + ((size_t)bh * DK + rV) * SEQ + cV;
  f16* lV = vt_lds + (wid << 9);

  for (int kv0 = 0; kv0 < SEQ; kv0 += 128) {
    __syncthreads();
    #pragma unroll
    for (int it = 0; it < 4; ++it) {
      gload_lds16(gK + (size_t)(kv0 + it * 32) * DK, lK + it * 2048);
      gload_lds16(gV + (size_t)(it * 16) * SEQ + kv0, lV + it * 2048);
    }
    __syncthreads();

    f32x4 accs[8];
    #pragma unroll
    for (int n = 0; n < 8; n++) {
      #pragma unroll
      for (int e = 0; e < 4; e++) accs[n][e] = 0.f;
    }
    __builtin_amdgcn_s_setprio(1);
    #pragma unroll
    for (int n = 0; n < 8; n++) {
      #pragma unroll
      for (int kk = 0; kk < 2; kk++) {
        int rowk = n * 16 + l15;
        bf16x8 kf = *(const bf16x8*)(kt_lds + rowk * 64 + ((((kk << 2) + l4) ^ (rowk & 7)) << 3));
        accs[n] = __builtin_amdgcn_mfma_f32_16x16x32_bf16(kf, qf[kk], accs[n], 0, 0, 0);
      }
    }
    __builtin_amdgcn_s_setprio(0);

    float mloc = -1e30f;
    #pragma unroll
    for (int n = 0; n < 8; n++)
      #pragma unroll
      for (int j = 0; j < 4; j++) mloc = fmaxf(mloc, accs[n][j]);
    float mt = fmaxf(mloc, __shfl_xor(mloc, 16, 64));
    mt = fmaxf(mt, __shfl_xor(mt, 32, 64));
    if (__any(mt > m_run + 8.0f)) {
      float mn = fmaxf(m_run, mt);
      float sc = exp2f(m_run - mn);
      m_run = mn;
      float scr0 = __shfl(sc, l4 * 20 + 0, 64);
      float scr1 = __shfl(sc, l4 * 20 + 1, 64);
      float scr2 = __shfl(sc, l4 * 20 + 2, 64);
      float scr3 = __shfl(sc, l4 * 20 + 3, 64);
      #pragma unroll
      for (int nd = 0; nd < 4; nd++) {
        acc_o[nd][0] *= scr0; acc_o[nd][1] *= scr1;
        acc_o[nd][2] *= scr2; acc_o[nd][3] *= scr3;
      }
      acc_l[0] *= scr0; acc_l[1] *= scr1; acc_l[2] *= scr2; acc_l[3] *= scr3;
    }
    // P = exp2(S - m_run) -> f16 A-fragments (lane-local, no exchange)
    f16x4 pa[8];
    #pragma unroll
    for (int n = 0; n < 8; n++)
      #pragma unroll
      for (int j = 0; j < 4; j++)
        pa[n][j] = (f16)exp2f(accs[n][j] - m_run);

    // O += P @ V, l += P @ ones
    __builtin_amdgcn_s_setprio(1);
    #pragma unroll
    for (int kk = 0; kk < 8; kk++) {
      #pragma unroll
      for (int nd = 0; nd < 4; nd++) {
        int rowv = nd * 16 + l15;
        int g = (kk << 1) + (l4 >> 1);
        f16x4 vf = *(const f16x4*)((const char*)vt_lds + rowv * 256 +
                                   (((g ^ (rowv & 15)) << 4) + ((l4 & 1) << 3)));
        acc_o[nd] = __builtin_amdgcn_mfma_f32_16x16x16f16(pa[kk], vf, acc_o[nd], 0, 0, 0);
      }
      acc_l = __builtin_amdgcn_mfma_f32_16x16x16f16(pa[kk], vones, acc_l, 0, 0, 0);
    }
    __builtin_amdgcn_s_setprio(0);
  }

  float rl0 = 1.0f / acc_l[0], rl1 = 1.0f / acc_l[1];
  float rl2 = 1.0f / acc_l[2], rl3 = 1.0f / acc_l[3];
  int bb = bh >> 4, hh = bh & 15;
  #pragma unroll
  for (int nd = 0; nd < 4; nd++) {
    int d = nd * 16 + l15;
    int rowb = t0 + wid * 16 + l4 * 4;
    o[((size_t)bb * SEQ + rowb + 0) * D_MODEL + hh * DK + d] = (bf16)(acc_o[nd][0] * rl0);
    o[((size_t)bb * SEQ + rowb + 1) * D_MODEL + hh * DK + d] = (bf16)(acc_o[nd][1] * rl1);
    o[((size_t)bb * SEQ + rowb + 2) * D_MODEL + hh * DK + d] = (bf16)(acc_o[nd][2] * rl2);
    o[((size_t)bb * SEQ + rowb + 3) * D_MODEL + hh * DK + d] = (bf16)(acc_o[nd][3] * rl3);
  }
}

// ---------------- launch ----------------
extern "C" void kernel_launch(void* const* d_in, const int* in_sizes, int n_in,
                              void* d_out, int out_size, void* d_ws, size_t ws_size,
                              hipStream_t stream) {
  const float* x    = (const float*)d_in[0];
  const float* ln1g = (const float*)d_in[1];
  const float* ln1b = (const float*)d_in[2];
  const float* wq   = (const float*)d_in[3];
  const float* bq   = (const float*)d_in[4];
  const float* wk   = (const float*)d_in[5];
  const float* bk   = (const float*)d_in[6];
  const float* wv   = (const float*)d_in[7];
  const float* bv   = (const float*)d_in[8];
  const float* wo   = (const float*)d_in[9];
  const float* bo   = (const float*)d_in[10];
  const float* ln2g = (const float*)d_in[11];
  const float* ln2b = (const float*)d_in[12];
  const float* w1   = (const float*)d_in[13];
  const float* b1   = (const float*)d_in[14];
  const float* w2   = (const float*)d_in[15];
  const float* b2   = (const float*)d_in[16];
  float* out = (float*)d_out;

  char* ws = (char*)d_ws;
  bf16* wqkv_b = (bf16*)(ws);                          // 6MB
  bf16* wo_b   = (bf16*)(ws + ((size_t)6  << 20));     // 2MB
  bf16* w1_b   = (bf16*)(ws + ((size_t)8  << 20));     // 8MB
  bf16* w2_b   = (bf16*)(ws + ((size_t)16 << 20));     // 8MB
  bf16* h_b    = (bf16*)(ws + ((size_t)24 << 20));     // 16MB
  bf16* qkv_b  = (bf16*)(ws + ((size_t)40 << 20));     // 48MB q|k|vT(f16)
  bf16* o_b    = (bf16*)(ws + ((size_t)88 << 20));     // 16MB
  bf16* ffn1_b = (bf16*)(ws + ((size_t)40 << 20));     // 64MB (over dead q,k,v,o)
  float* bqkv  = (float*)(ws + ((size_t)104 << 20));   // 12KB

  cast_w<<<1024, 256, 0, stream>>>(wq, wqkv_b, 1 << 20);
  cast_w<<<1024, 256, 0, stream>>>(wk, wqkv_b + (1 << 20), 1 << 20);
  cast_w<<<1024, 256, 0, stream>>>(wv, wqkv_b + (2 << 20), 1 << 20);
  cast_w<<<1024, 256, 0, stream>>>(wo, wo_b, 1 << 20);
  cast_w<<<4096, 256, 0, stream>>>(w1, w1_b, 1 << 22);
  cast_w<<<4096, 256, 0, stream>>>(w2, w2_b, 1 << 22);
  hipMemcpyAsync(bqkv,        bq, 4096, hipMemcpyDeviceToDevice, stream);
  hipMemcpyAsync(bqkv + 1024, bk, 4096, hipMemcpyDeviceToDevice, stream);
  hipMemcpyAsync(bqkv + 2048, bv, 4096, hipMemcpyDeviceToDevice, stream);

  ln_kernel<<<MTOK, 256, 0, stream>>>(x, ln1g, ln1b, h_b);
  gemm256<EP_QKV><<<768, 512, 0, stream>>>(h_b, wqkv_b, bqkv, nullptr, nullptr,
                                           qkv_b, MTOK, 3072, 1024);
  attn_kernel<<<NBH * 32, 256, 0, stream>>>(qkv_b, qkv_b + (size_t)NBH * SEQ * DK,
                                            (const f16*)(qkv_b + (size_t)2 * NBH * SEQ * DK),
                                            o_b);
  gemm256<EP_RESID><<<256, 512, 0, stream>>>(o_b, wo_b, bo, x, out, nullptr,
                                             MTOK, 1024, 1024);
  ln_kernel<<<MTOK, 256, 0, stream>>>(out, ln2g, ln2b, h_b);
  gemm256<EP_GELU><<<1024, 512, 0, stream>>>(h_b, w1_b, b1, nullptr, nullptr,
                                             ffn1_b, MTOK, 4096, 1024);
  gemm256<EP_RESID><<<256, 512, 0, stream>>>(ffn1_b, w2_b, b2, out, out, nullptr,
                                             MTOK, 1024, 4096);
}

// Round 7
// 473.629 us; speedup vs baseline: 1.0693x; 1.0693x over previous
//
#include <hip/hip_runtime.h>
#include <math.h>

// EncoderBlock: pre-LN attention + FFN, bf16 MFMA compute, fp32 residual spine.
// B=4 T=2048 D=1024 H=16 dk=64 DFF=4096
// R3: swapped QK^T -> lane-local P; PV via 16x16x16f16 from P registers.
// R6: GEMM rebuilt on m201 geometry: 8 waves 2Mx4N; cfg0 256x256 BK32 wave
//     128x64 (FFN1), cfg1 128x256 BK64 wave 64x64 (full grids for N=1024/3072).
//     B-frags register-cached per K-tile; 2 phases/K-tile; 3-buffer ring with
//     vmcnt(L) counted waits; both-sides XOR swizzle; XCD block swizzle.

#define D_MODEL 1024
#define D_FF    4096
#define NH      16
#define BATCH   4
#define SEQ     2048
#define DK      64
#define MTOK    (BATCH*SEQ)   // 8192
#define NBH     (BATCH*NH)    // 64

typedef __bf16 bf16;
typedef _Float16 f16;
typedef bf16  bf16x4 __attribute__((ext_vector_type(4)));
typedef bf16  bf16x8 __attribute__((ext_vector_type(8)));
typedef f16   f16x4  __attribute__((ext_vector_type(4)));
typedef float f32x4  __attribute__((ext_vector_type(4)));

__device__ __forceinline__ void gload_lds16(const void* g, void* l) {
  __builtin_amdgcn_global_load_lds(
      (__attribute__((address_space(1))) void*)g,
      (__attribute__((address_space(3))) void*)l, 16, 0, 0);
}

#define BAR() __builtin_amdgcn_s_barrier()
#define WAIT_VM0() do { asm volatile("s_waitcnt vmcnt(0)" ::: "memory"); \
  __builtin_amdgcn_sched_barrier(0); } while (0)
#define WAIT_LGKM0() do { asm volatile("s_waitcnt lgkmcnt(0)" ::: "memory"); } while (0)

// ---------------- fp32 -> bf16 cast (weights) ----------------
__global__ __launch_bounds__(256) void cast_w(const float* __restrict__ s,
                                              bf16* __restrict__ d, int n) {
  int i = (blockIdx.x * 256 + threadIdx.x) * 4;
  if (i >= n) return;
  float4 v = *(const float4*)(s + i);
  bf16x4 o;
  o[0] = (bf16)v.x; o[1] = (bf16)v.y; o[2] = (bf16)v.z; o[3] = (bf16)v.w;
  *(bf16x4*)(d + i) = o;
}

// ---------------- LayerNorm (fp32 in, bf16 out) ----------------
__global__ __launch_bounds__(256) void ln_kernel(const float* __restrict__ x,
                                                 const float* __restrict__ g,
                                                 const float* __restrict__ b,
                                                 bf16* __restrict__ out) {
  int row = blockIdx.x;
  int tid = threadIdx.x;
  const float* xr = x + (size_t)row * D_MODEL;
  float4 v = *(const float4*)(xr + tid * 4);
  float s  = v.x + v.y + v.z + v.w;
  float sq = v.x*v.x + v.y*v.y + v.z*v.z + v.w*v.w;
  #pragma unroll
  for (int off = 1; off < 64; off <<= 1) {
    s  += __shfl_xor(s,  off, 64);
    sq += __shfl_xor(sq, off, 64);
  }
  __shared__ float ls[4], lq[4];
  int wid = tid >> 6, lane = tid & 63;
  if (lane == 0) { ls[wid] = s; lq[wid] = sq; }
  __syncthreads();
  s  = ls[0] + ls[1] + ls[2] + ls[3];
  sq = lq[0] + lq[1] + lq[2] + lq[3];
  float mu   = s * (1.0f / D_MODEL);
  float var  = sq * (1.0f / D_MODEL) - mu * mu;
  float rstd = rsqrtf(var + 1e-5f);
  float4 gv = *(const float4*)(g + tid * 4);
  float4 bv = *(const float4*)(b + tid * 4);
  bf16x4 o;
  o[0] = (bf16)((v.x - mu) * rstd * gv.x + bv.x);
  o[1] = (bf16)((v.y - mu) * rstd * gv.y + bv.y);
  o[2] = (bf16)((v.z - mu) * rstd * gv.z + bv.z);
  o[3] = (bf16)((v.w - mu) * rstd * gv.w + bv.w);
  *(bf16x4*)(out + (size_t)row * D_MODEL + tid * 4) = o;
}

// ---------------- GEMM: C[M,N] = A[M,K] @ W[N,K]^T (+bias, epilogue) --------
enum { EP_QKV = 0, EP_RESID = 1, EP_GELU = 2 };

#define QSCALE 0.18033688011112042f  // (1/8) * log2(e)

// CFG 0: BM=256 BN=256 BK=32, wave tile 128x64 (ratio-optimal, grid = M/256*N/256)
// CFG 1: BM=128 BN=256 BK=64, wave tile 64x64  (full grids when N/256 small)
template <int EP, int CFG>
__global__ __launch_bounds__(512) void gemm8p(
    const bf16* __restrict__ A, const bf16* __restrict__ W,
    const float* __restrict__ bias,
    const float* __restrict__ resid,
    float* __restrict__ out_f32,
    bf16* __restrict__ out_bf,
    int M, int N, int K) {
  constexpr int BM  = CFG ? 128 : 256;
  constexpr int BK  = CFG ? 64 : 32;
  constexpr int WM  = CFG ? 64 : 128;     // wave-tile rows
  constexpr int FRN = WM / 16;            // frag rows per wave (4 or 8)
  constexpr int FRP = FRN / 2;            // frag rows per phase
  constexpr int KKN = BK / 32;            // k-steps per K-tile (2 or 1)
  constexpr int RB  = BK * 2;             // LDS row bytes (128 or 64)
  constexpr int GR  = RB / 16;            // 16B granules per row (8 or 4)
  constexpr int RSH = CFG ? 7 : 6;        // log2(RB)
  constexpr int AB  = 16384;              // A region bytes (BM*BK*2 both cfgs)
  constexpr int TB  = AB + 256 * BK * 2;  // tile bytes (49152 or 32768)
  constexpr int L   = TB / 8192;          // gloads per thread per K-tile (6 or 4)
  constexpr int Lh  = L / 2;

  __shared__ char lds[3 * TB];

  int tiles_n = N >> 8;
  int nwg = (M / BM) * tiles_n;
  int bid = blockIdx.x;
  int swz = (bid & 7) * (nwg >> 3) + (bid >> 3);
  int bm = swz / tiles_n, bn = swz % tiles_n;
  int m0 = bm * BM, n0 = bn << 8;
  int tid = threadIdx.x, wid = tid >> 6, lane = tid & 63;
  int wm = wid >> 2, wn = wid & 3;        // 2M x 4N
  int l15 = lane & 15, l4 = lane >> 4;

  f32x4 acc[FRN][4];
  #pragma unroll
  for (int i = 0; i < FRN; i++)
    #pragma unroll
    for (int j = 0; j < 4; j++)
      #pragma unroll
      for (int e = 0; e < 4; e++) acc[i][j][e] = 0.f;

  // stage `part` (0/1) of K-tile kt into ring buffer nb
  auto STAGE = [&](int kt, int nb, int part) {
    char* buf = lds + nb * TB;
    #pragma unroll
    for (int l = part * Lh; l < part * Lh + Lh; ++l) {
      bool isA = l < 2;
      int o = (isA ? l : l - 2) * 8192 + tid * 16;
      int row = o >> RSH;
      int g = (o >> 4) & (GR - 1);
      int gs = g ^ (CFG ? (row & 7) : ((row >> 1) & 3));
      const bf16* src = (isA ? A + (size_t)(m0 + row) * K
                             : W + (size_t)(n0 + row) * K) + kt * BK + gs * 8;
      gload_lds16(src, buf + (isA ? 0 : AB) + o);
    }
  };

  int nt = K / BK;
  STAGE(0, 0, 0); STAGE(0, 0, 1);
  STAGE(1, 1, 0); STAGE(1, 1, 1);
  if constexpr (CFG) { asm volatile("s_waitcnt vmcnt(6)" ::: "memory"); }
  else               { asm volatile("s_waitcnt vmcnt(4)" ::: "memory"); }
  __builtin_amdgcn_sched_barrier(0);
  BAR();

  bf16x8 bfr[4][KKN];   // B fragments, held across both phases
  for (int t = 0; t < nt; ++t) {
    int cb = t % 3, nb = cb >= 1 ? cb - 1 : 2;  // (t+2)%3
    bool ds_ = (t + 2) < nt;
    const char* bc = lds + cb * TB;

    // ---- phase 0: A-frags fr[0..FRP) + ALL B-frags; stage part 0 ----
    bf16x8 af[FRP][KKN];
    #pragma unroll
    for (int f = 0; f < FRP; ++f)
      #pragma unroll
      for (int kk = 0; kk < KKN; ++kk) {
        int row = wm * WM + f * 16 + l15;
        int g = (kk * 4 + l4) ^ (CFG ? (row & 7) : ((row >> 1) & 3));
        af[f][kk] = *(const bf16x8*)(bc + row * RB + g * 16);
      }
    #pragma unroll
    for (int fc = 0; fc < 4; ++fc)
      #pragma unroll
      for (int kk = 0; kk < KKN; ++kk) {
        int row = wn * 64 + fc * 16 + l15;
        int g = (kk * 4 + l4) ^ (CFG ? (row & 7) : ((row >> 1) & 3));
        bfr[fc][kk] = *(const bf16x8*)(bc + AB + row * RB + g * 16);
      }
    if (ds_) STAGE(t + 2, nb, 0);
    BAR();
    WAIT_LGKM0();
    __builtin_amdgcn_s_setprio(1);
    #pragma unroll
    for (int f = 0; f < FRP; ++f)
      #pragma unroll
      for (int fc = 0; fc < 4; ++fc)
        #pragma unroll
        for (int kk = 0; kk < KKN; ++kk)
          acc[f][fc] = __builtin_amdgcn_mfma_f32_16x16x32_bf16(af[f][kk], bfr[fc][kk],
                                                               acc[f][fc], 0, 0, 0);
    __builtin_amdgcn_s_setprio(0);
    BAR();

    // ---- phase 1: A-frags fr[FRP..FRN); stage part 1 ----
    bf16x8 af1[FRP][KKN];
    #pragma unroll
    for (int f = 0; f < FRP; ++f)
      #pragma unroll
      for (int kk = 0; kk < KKN; ++kk) {
        int row = wm * WM + (FRP + f) * 16 + l15;
        int g = (kk * 4 + l4) ^ (CFG ? (row & 7) : ((row >> 1) & 3));
        af1[f][kk] = *(const bf16x8*)(bc + row * RB + g * 16);
      }
    if (ds_) STAGE(t + 2, nb, 1);
    BAR();
    WAIT_LGKM0();
    __builtin_amdgcn_s_setprio(1);
    #pragma unroll
    for (int f = 0; f < FRP; ++f)
      #pragma unroll
      for (int fc = 0; fc < 4; ++fc)
        #pragma unroll
        for (int kk = 0; kk < KKN; ++kk)
          acc[FRP + f][fc] = __builtin_amdgcn_mfma_f32_16x16x32_bf16(af1[f][kk], bfr[fc][kk],
                                                                     acc[FRP + f][fc], 0, 0, 0);
    __builtin_amdgcn_s_setprio(0);
    if (t < nt - 2) {
      if constexpr (CFG) { asm volatile("s_waitcnt vmcnt(6)" ::: "memory"); }
      else               { asm volatile("s_waitcnt vmcnt(4)" ::: "memory"); }
      __builtin_amdgcn_sched_barrier(0);
    } else if (t == nt - 2) {
      WAIT_VM0();
    }
    BAR();
  }

  // ----- epilogue -----
  if (EP == EP_QKV) {
    #pragma unroll
    for (int i = 0; i < FRN; i++)
      #pragma unroll
      for (int j = 0; j < 4; j++) {
        int gm0 = m0 + wm * WM + i * 16 + (l4 << 2);
        int gn  = n0 + wn * 64 + j * 16 + l15;
        int which = gn >> 10;
        int nn = gn & 1023, head = nn >> 6, d = nn & 63;
        int bb = gm0 >> 11, t = gm0 & 2047;
        float bv = bias[gn];
        if (which == 2) {
          f16x4 pk;
          #pragma unroll
          for (int jj = 0; jj < 4; jj++) pk[jj] = (f16)(acc[i][j][jj] + bv);
          *(f16x4*)((f16*)out_bf + (size_t)2 * NBH * SEQ * DK +
                    ((size_t)(bb * NH + head) * DK + d) * SEQ + t) = pk;
        } else {
          float scale = (which == 0) ? QSCALE : 1.0f;
          #pragma unroll
          for (int jj = 0; jj < 4; jj++) {
            float cv = (acc[i][j][jj] + bv) * scale;
            size_t idx = (size_t)which * (NBH * SEQ * DK) +
                         ((size_t)(bb * NH + head) * SEQ + (t + jj)) * DK + d;
            out_bf[idx] = (bf16)cv;
          }
        }
      }
  } else {
    #pragma unroll
    for (int i = 0; i < FRN; i++)
      #pragma unroll
      for (int j = 0; j < 4; j++)
        #pragma unroll
        for (int jj = 0; jj < 4; jj++) {
          int gm = m0 + wm * WM + i * 16 + (l4 << 2) + jj;
          int gn = n0 + wn * 64 + j * 16 + l15;
          float cv = acc[i][j][jj] + bias[gn];
          if (EP == EP_RESID) {
            size_t idx = (size_t)gm * N + gn;
            out_f32[idx] = resid[idx] + cv;
          } else {
            float ge = 0.5f * cv * (1.0f + erff(cv * 0.70710678118654752f));
            out_bf[(size_t)gm * N + gn] = (bf16)ge;
          }
        }
  }
}

// ---------------- Flash attention (register-resident P) ----------------
__global__ __launch_bounds__(256) void attn_kernel(
    const bf16* __restrict__ q, const bf16* __restrict__ k,
    const f16* __restrict__ vt, bf16* __restrict__ o) {
  __shared__ bf16 kt_lds[128 * 64];     // [kv][dk], granule16 ^= row&7
  __shared__ f16  vt_lds[64 * 128];     // [d][kv],  granule16 ^= row&15
  int bid = blockIdx.x;
  int bh = bid >> 5;
  int qt = bid & 31;
  int t0 = qt << 6;
  int tid = threadIdx.x, wid = tid >> 6, lane = tid & 63;
  int l15 = lane & 15, l4 = lane >> 4;

  const bf16* qbase = q + ((size_t)bh * SEQ + t0 + wid * 16 + l15) * DK;
  bf16x8 qf[2];
  qf[0] = *(const bf16x8*)(qbase + (l4 << 3));
  qf[1] = *(const bf16x8*)(qbase + 32 + (l4 << 3));

  const f16x4 vones = {(f16)1.f, (f16)1.f, (f16)1.f, (f16)1.f};
  float m_run = -1e30f;
  f32x4 acc_o[4];
  f32x4 acc_l;
  #pragma unroll
  for (int nd = 0; nd < 4; nd++)
    #pragma unroll
    for (int e = 0; e < 4; e++) acc_o[nd][e] = 0.f;
  #pragma unroll
  for (int e = 0; e < 4; e++) acc_l[e] = 0.f;

  int rK = tid >> 3;
  int cK = ((tid & 7) ^ (rK & 7)) << 3;
  const bf16* gK = k + ((size_t)bh * SEQ + rK) * DK + cK;
  bf16* lK = kt_lds + (wid << 9);
  int rV = tid >> 4;
  int cV = ((tid & 15) ^ rV) << 3;
  const f16* gV = vt + ((size_t)bh * DK + rV) * SEQ + cV;
  f16* lV = vt_lds + (wid << 9);

  for (int kv0 = 0; kv0 < SEQ; kv0 += 128) {
    __syncthreads();
    #pragma unroll
    for (int it = 0; it < 4; ++it) {
      gload_lds16(gK + (size_t)(kv0 + it * 32) * DK, lK + it * 2048);
      gload_lds16(gV + (size_t)(it * 16) * SEQ + kv0, lV + it * 2048);
    }
    __syncthreads();

    f32x4 accs[8];
    #pragma unroll
    for (int n = 0; n < 8; n++) {
      #pragma unroll
      for (int e = 0; e < 4; e++) accs[n][e] = 0.f;
    }
    __builtin_amdgcn_s_setprio(1);
    #pragma unroll
    for (int n = 0; n < 8; n++) {
      #pragma unroll
      for (int kk = 0; kk < 2; kk++) {
        int rowk = n * 16 + l15;
        bf16x8 kf = *(const bf16x8*)(kt_lds + rowk * 64 + ((((kk << 2) + l4) ^ (rowk & 7)) << 3));
        accs[n] = __builtin_amdgcn_mfma_f32_16x16x32_bf16(kf, qf[kk], accs[n], 0, 0, 0);
      }
    }
    __builtin_amdgcn_s_setprio(0);

    float mloc = -1e30f;
    #pragma unroll
    for (int n = 0; n < 8; n++)
      #pragma unroll
      for (int j = 0; j < 4; j++) mloc = fmaxf(mloc, accs[n][j]);
    float mt = fmaxf(mloc, __shfl_xor(mloc, 16, 64));
    mt = fmaxf(mt, __shfl_xor(mt, 32, 64));
    if (__any(mt > m_run + 8.0f)) {
      float mn = fmaxf(m_run, mt);
      float sc = exp2f(m_run - mn);
      m_run = mn;
      float scr0 = __shfl(sc, l4 * 20 + 0, 64);
      float scr1 = __shfl(sc, l4 * 20 + 1, 64);
      float scr2 = __shfl(sc, l4 * 20 + 2, 64);
      float scr3 = __shfl(sc, l4 * 20 + 3, 64);
      #pragma unroll
      for (int nd = 0; nd < 4; nd++) {
        acc_o[nd][0] *= scr0; acc_o[nd][1] *= scr1;
        acc_o[nd][2] *= scr2; acc_o[nd][3] *= scr3;
      }
      acc_l[0] *= scr0; acc_l[1] *= scr1; acc_l[2] *= scr2; acc_l[3] *= scr3;
    }
    f16x4 pa[8];
    #pragma unroll
    for (int n = 0; n < 8; n++)
      #pragma unroll
      for (int j = 0; j < 4; j++)
        pa[n][j] = (f16)exp2f(accs[n][j] - m_run);

    __builtin_amdgcn_s_setprio(1);
    #pragma unroll
    for (int kk = 0; kk < 8; kk++) {
      #pragma unroll
      for (int nd = 0; nd < 4; nd++) {
        int rowv = nd * 16 + l15;
        int g = (kk << 1) + (l4 >> 1);
        f16x4 vf = *(const f16x4*)((const char*)vt_lds + rowv * 256 +
                                   (((g ^ (rowv & 15)) << 4) + ((l4 & 1) << 3)));
        acc_o[nd] = __builtin_amdgcn_mfma_f32_16x16x16f16(pa[kk], vf, acc_o[nd], 0, 0, 0);
      }
      acc_l = __builtin_amdgcn_mfma_f32_16x16x16f16(pa[kk], vones, acc_l, 0, 0, 0);
    }
    __builtin_amdgcn_s_setprio(0);
  }

  float rl0 = 1.0f / acc_l[0], rl1 = 1.0f / acc_l[1];
  float rl2 = 1.0f / acc_l[2], rl3 = 1.0f / acc_l[3];
  int bb = bh >> 4, hh = bh & 15;
  #pragma unroll
  for (int nd = 0; nd < 4; nd++) {
    int d = nd * 16 + l15;
    int rowb = t0 + wid * 16 + l4 * 4;
    o[((size_t)bb * SEQ + rowb + 0) * D_MODEL + hh * DK + d] = (bf16)(acc_o[nd][0] * rl0);
    o[((size_t)bb * SEQ + rowb + 1) * D_MODEL + hh * DK + d] = (bf16)(acc_o[nd][1] * rl1);
    o[((size_t)bb * SEQ + rowb + 2) * D_MODEL + hh * DK + d] = (bf16)(acc_o[nd][2] * rl2);
    o[((size_t)bb * SEQ + rowb + 3) * D_MODEL + hh * DK + d] = (bf16)(acc_o[nd][3] * rl3);
  }
}

// ---------------- launch ----------------
extern "C" void kernel_launch(void* const* d_in, const int* in_sizes, int n_in,
                              void* d_out, int out_size, void* d_ws, size_t ws_size,
                              hipStream_t stream) {
  const float* x    = (const float*)d_in[0];
  const float* ln1g = (const float*)d_in[1];
  const float* ln1b = (const float*)d_in[2];
  const float* wq   = (const float*)d_in[3];
  const float* bq   = (const float*)d_in[4];
  const float* wk   = (const float*)d_in[5];
  const float* bk   = (const float*)d_in[6];
  const float* wv   = (const float*)d_in[7];
  const float* bv   = (const float*)d_in[8];
  const float* wo   = (const float*)d_in[9];
  const float* bo   = (const float*)d_in[10];
  const float* ln2g = (const float*)d_in[11];
  const float* ln2b = (const float*)d_in[12];
  const float* w1   = (const float*)d_in[13];
  const float* b1   = (const float*)d_in[14];
  const float* w2   = (const float*)d_in[15];
  const float* b2   = (const float*)d_in[16];
  float* out = (float*)d_out;

  char* ws = (char*)d_ws;
  bf16* wqkv_b = (bf16*)(ws);                          // 6MB
  bf16* wo_b   = (bf16*)(ws + ((size_t)6  << 20));     // 2MB
  bf16* w1_b   = (bf16*)(ws + ((size_t)8  << 20));     // 8MB
  bf16* w2_b   = (bf16*)(ws + ((size_t)16 << 20));     // 8MB
  bf16* h_b    = (bf16*)(ws + ((size_t)24 << 20));     // 16MB
  bf16* qkv_b  = (bf16*)(ws + ((size_t)40 << 20));     // 48MB q|k|vT(f16)
  bf16* o_b    = (bf16*)(ws + ((size_t)88 << 20));     // 16MB
  bf16* ffn1_b = (bf16*)(ws + ((size_t)40 << 20));     // 64MB (over dead q,k,v,o)
  float* bqkv  = (float*)(ws + ((size_t)104 << 20));   // 12KB

  cast_w<<<1024, 256, 0, stream>>>(wq, wqkv_b, 1 << 20);
  cast_w<<<1024, 256, 0, stream>>>(wk, wqkv_b + (1 << 20), 1 << 20);
  cast_w<<<1024, 256, 0, stream>>>(wv, wqkv_b + (2 << 20), 1 << 20);
  cast_w<<<1024, 256, 0, stream>>>(wo, wo_b, 1 << 20);
  cast_w<<<4096, 256, 0, stream>>>(w1, w1_b, 1 << 22);
  cast_w<<<4096, 256, 0, stream>>>(w2, w2_b, 1 << 22);
  hipMemcpyAsync(bqkv,        bq, 4096, hipMemcpyDeviceToDevice, stream);
  hipMemcpyAsync(bqkv + 1024, bk, 4096, hipMemcpyDeviceToDevice, stream);
  hipMemcpyAsync(bqkv + 2048, bv, 4096, hipMemcpyDeviceToDevice, stream);

  ln_kernel<<<MTOK, 256, 0, stream>>>(x, ln1g, ln1b, h_b);
  gemm8p<EP_QKV, 1><<<768, 512, 0, stream>>>(h_b, wqkv_b, bqkv, nullptr, nullptr,
                                             qkv_b, MTOK, 3072, 1024);
  attn_kernel<<<NBH * 32, 256, 0, stream>>>(qkv_b, qkv_b + (size_t)NBH * SEQ * DK,
                                            (const f16*)(qkv_b + (size_t)2 * NBH * SEQ * DK),
                                            o_b);
  gemm8p<EP_RESID, 1><<<256, 512, 0, stream>>>(o_b, wo_b, bo, x, out, nullptr,
                                               MTOK, 1024, 1024);
  ln_kernel<<<MTOK, 256, 0, stream>>>(out, ln2g, ln2b, h_b);
  gemm8p<EP_GELU, 0><<<512, 512, 0, stream>>>(h_b, w1_b, b1, nullptr, nullptr,
                                              ffn1_b, MTOK, 4096, 1024);
  gemm8p<EP_RESID, 1><<<256, 512, 0, stream>>>(ffn1_b, w2_b, b2, out, out, nullptr,
                                               MTOK, 1024, 4096);
}